// Round 2
// baseline (336.384 us; speedup 1.0000x reference)
//
#include <hip/hip_runtime.h>
#include <hip/hip_bf16.h>

#define NB 8192
#define NT 50

__device__ __forceinline__ float leaky(float x) { return x > 0.0f ? x : 0.3f * x; }

__device__ __forceinline__ float idm_act_f(float v, float dv, float dx,
                                           float inv_v0, float tg, float jam,
                                           float amax, float inv_gd) {
    dx = fminf(fmaxf(dx, 0.1f), 500.0f);
    float gap = tg * v + v * dv * inv_gd;
    float dg = jam + fmaxf(gap, 0.0f);
    float r = v * inv_v0;
    float r2 = r * r;
    float r4 = r2 * r2;
    float q = dg / dx;
    float act = amax * (1.0f - r4 - q * q);
    return fminf(fmaxf(act, -6.0f), 6.0f);
}

extern "C" __global__ __launch_bounds__(256, 2)
void idm_rollout_kernel(const float* __restrict__ idm_params,
                        const float* __restrict__ proj_latent,
                        const float* __restrict__ enc_h,
                        const float* __restrict__ idm_s,
                        const float* __restrict__ merger_cs,
                        const float* __restrict__ scaler_mean,
                        const float* __restrict__ scaler_var,
                        const float* __restrict__ W1,
                        const float* __restrict__ b1,
                        const float* __restrict__ W2,
                        const float* __restrict__ b2,
                        const float* __restrict__ Wf,
                        const float* __restrict__ bfp,
                        const float* __restrict__ Wm,
                        const float* __restrict__ bmp,
                        float* __restrict__ out)
{
    __shared__ float s_w2[128 * 128];   // [k][j]
    __shared__ float s_w1e[8 * 128];    // env rows, inv_std folded
    __shared__ float s_w1m[3 * 128];    // mc rows
    __shared__ float s_h1[16 * 132];    // per-group h1, stride 132 (bank stagger)

    const int tid = threadIdx.x;

    // ---- stage weights into LDS ----
    {
        const float4* src = (const float4*)W2;
        float4* dst = (float4*)s_w2;
        #pragma unroll
        for (int i = 0; i < 16; ++i) dst[tid + 256 * i] = src[tid + 256 * i];
    }
    {   // 8 env rows of W1 (rows 256..263), scale by 1/sqrt(var[k])
        const int k = tid >> 5;             // 0..7
        const float is = 1.0f / sqrtf(scaler_var[k]);
        const float4 w = *(const float4*)&W1[(256 + k) * 128 + ((tid << 2) & 127)];
        float4 o; o.x = w.x * is; o.y = w.y * is; o.z = w.z * is; o.w = w.w * is;
        *(float4*)&s_w1e[tid << 2] = o;
    }
    if (tid < 96) {   // 3 mc rows of W1 (rows 264..266)
        const int k = tid >> 5;             // 0..2
        const int j = (tid << 2) & 127;
        *(float4*)&s_w1m[tid << 2] = *(const float4*)&W1[(264 + k) * 128 + j];
    }
    __syncthreads();

    // ---- lane geometry: 16 lanes per batch element ----
    const int lane = tid & 63;
    const int sidx = lane & 15;          // slice within group
    const int grp  = lane >> 4;          // 0..3 group in wave
    const int wv   = tid >> 6;           // 0..3 wave in block
    const int bl   = wv * 4 + grp;       // 0..15 local batch element
    const int b    = blockIdx.x * 16 + bl;
    const int jlo  = sidx * 4;
    const int jhi  = 64 + sidx * 4;
    float* myh1 = &s_h1[bl * 132];

    // ---- per-element params ----
    const float p_v0   = idm_params[b * 5 + 0];
    const float p_tg   = idm_params[b * 5 + 1];
    const float p_jam  = idm_params[b * 5 + 2];
    const float p_amax = idm_params[b * 5 + 3];
    const float p_amin = idm_params[b * 5 + 4];
    const float inv_v0 = 1.0f / p_v0;
    const float inv_gd = 1.0f / (2.0f * sqrtf(p_amax * p_amin));

    // ---- per-lane weight slices in registers ----
    const float4 wf_lo = *(const float4*)&Wf[jlo];
    const float4 wf_hi = *(const float4*)&Wf[jhi];
    const float4 wm_lo = *(const float4*)&Wm[jlo];
    const float4 wm_hi = *(const float4*)&Wm[jhi];
    const float4 b2_lo = *(const float4*)&b2[jlo];
    const float4 b2_hi = *(const float4*)&b2[jhi];
    const float bfv = bfp[0];
    const float bmv = bmp[0];

    // ---- hpre: time-invariant part of layer-1 preactivation ----
    float hp[8];
    {
        const float4 b1lo = *(const float4*)&b1[jlo];
        const float4 b1hi = *(const float4*)&b1[jhi];
        hp[0] = b1lo.x; hp[1] = b1lo.y; hp[2] = b1lo.z; hp[3] = b1lo.w;
        hp[4] = b1hi.x; hp[5] = b1hi.y; hp[6] = b1hi.z; hp[7] = b1hi.w;
    }
    const float* projb = &proj_latent[b * 128];
    const float* ench  = &enc_h[b * 128];
    #pragma unroll 4
    for (int k = 0; k < 256; ++k) {
        const float x = (k < 128) ? projb[k] : ench[k - 128];
        const float4 wl = *(const float4*)&W1[k * 128 + jlo];
        const float4 wh = *(const float4*)&W1[k * 128 + jhi];
        hp[0] += x * wl.x; hp[1] += x * wl.y; hp[2] += x * wl.z; hp[3] += x * wl.w;
        hp[4] += x * wh.x; hp[5] += x * wh.y; hp[6] += x * wh.z; hp[7] += x * wh.w;
    }
    // fold -(mean*inv_std) @ W1env into hpre (s_w1e already has inv_std)
    #pragma unroll
    for (int k = 0; k < 8; ++k) {
        const float mk = scaler_mean[k];
        const float4 wl = *(const float4*)&s_w1e[k * 128 + jlo];
        const float4 wh = *(const float4*)&s_w1e[k * 128 + jhi];
        hp[0] -= mk * wl.x; hp[1] -= mk * wl.y; hp[2] -= mk * wl.z; hp[3] -= mk * wl.w;
        hp[4] -= mk * wh.x; hp[5] -= mk * wh.y; hp[6] -= mk * wh.z; hp[7] -= mk * wh.w;
    }

    // ---- carry init ----
    const float* srow = idm_s + (size_t)b * 714;   // 51*14
    const float* mrow = merger_cs + (size_t)b * 150;
    float ego_v = srow[0];
    float ego_a = srow[11];
    float ego_x = srow[3];
    float disp  = 0.0f;

    float* out_disp = out;
    float* out_act  = out + NB * 51;
    float* out_fat  = out + NB * (51 + 50);
    float* out_mat  = out + NB * (51 + 100);
    if (sidx == 0) out_disp[b * 51] = 0.0f;

    // prefetch t=0 scalars
    float c_fv = srow[1], c_mv = srow[2], c_fx = srow[4], c_mx = srow[5];
    float c_fa = srow[12], c_me = srow[13];
    float c_m0 = mrow[0], c_m1 = mrow[1], c_m2 = mrow[2];

    for (int t = 0; t < NT; ++t) {
        const float fv = c_fv, mv = c_mv, fx = c_fx, mx = c_mx, fa = c_fa, me = c_me;
        const float m0 = c_m0, m1 = c_m1, m2 = c_m2;
        if (t + 1 < NT) {
            const float* sp = srow + (t + 1) * 14;
            c_fv = sp[1]; c_mv = sp[2]; c_fx = sp[4]; c_mx = sp[5];
            c_fa = sp[12]; c_me = sp[13];
            const float* mp = mrow + (t + 1) * 3;
            c_m0 = mp[0]; c_m1 = mp[1]; c_m2 = mp[2];
        }

        const float ef_dx = fx - ego_x;
        const float em_dx = (mx - ego_x) * me + (1.0f - me) * 100.0f;
        const float ef_dv = ego_v - fv;
        const float em_dv = (ego_v - mv) * me;

        float env[8];
        env[0] = ego_a; env[1] = fa;    env[2] = ego_v; env[3] = fv;
        env[4] = ef_dv; env[5] = ef_dx; env[6] = em_dv; env[7] = em_dx;

        // ---- layer 1 (11 dynamic input rows) ----
        float h[8];
        #pragma unroll
        for (int i = 0; i < 8; ++i) h[i] = hp[i];
        #pragma unroll
        for (int k = 0; k < 8; ++k) {
            const float4 wl = *(const float4*)&s_w1e[k * 128 + jlo];
            const float4 wh = *(const float4*)&s_w1e[k * 128 + jhi];
            const float x = env[k];
            h[0] += x * wl.x; h[1] += x * wl.y; h[2] += x * wl.z; h[3] += x * wl.w;
            h[4] += x * wh.x; h[5] += x * wh.y; h[6] += x * wh.z; h[7] += x * wh.w;
        }
        {
            const float xs[3] = {m0, m1, m2};
            #pragma unroll
            for (int k = 0; k < 3; ++k) {
                const float4 wl = *(const float4*)&s_w1m[k * 128 + jlo];
                const float4 wh = *(const float4*)&s_w1m[k * 128 + jhi];
                const float x = xs[k];
                h[0] += x * wl.x; h[1] += x * wl.y; h[2] += x * wl.z; h[3] += x * wl.w;
                h[4] += x * wh.x; h[5] += x * wh.y; h[6] += x * wh.z; h[7] += x * wh.w;
            }
        }
        #pragma unroll
        for (int i = 0; i < 8; ++i) h[i] = leaky(h[i]);

        // exchange h1 within the 16-lane group (same wave -> in-order DS; fence
        // stops the compiler from reordering the reads above the writes)
        *(float4*)&myh1[jlo] = make_float4(h[0], h[1], h[2], h[3]);
        *(float4*)&myh1[jhi] = make_float4(h[4], h[5], h[6], h[7]);
        asm volatile("" ::: "memory");

        // ---- layer 2: h2 = leaky(h1 @ W2 + b2) ----
        float acc0 = 0, acc1 = 0, acc2 = 0, acc3 = 0;
        float acc4 = 0, acc5 = 0, acc6 = 0, acc7 = 0;
        #pragma unroll
        for (int kk = 0; kk < 128; kk += 4) {
            const float4 hq = *(const float4*)&myh1[kk];
            {
                const float4 wl = *(const float4*)&s_w2[(kk + 0) * 128 + jlo];
                const float4 wh = *(const float4*)&s_w2[(kk + 0) * 128 + jhi];
                acc0 += hq.x * wl.x; acc1 += hq.x * wl.y; acc2 += hq.x * wl.z; acc3 += hq.x * wl.w;
                acc4 += hq.x * wh.x; acc5 += hq.x * wh.y; acc6 += hq.x * wh.z; acc7 += hq.x * wh.w;
            }
            {
                const float4 wl = *(const float4*)&s_w2[(kk + 1) * 128 + jlo];
                const float4 wh = *(const float4*)&s_w2[(kk + 1) * 128 + jhi];
                acc0 += hq.y * wl.x; acc1 += hq.y * wl.y; acc2 += hq.y * wl.z; acc3 += hq.y * wl.w;
                acc4 += hq.y * wh.x; acc5 += hq.y * wh.y; acc6 += hq.y * wh.z; acc7 += hq.y * wh.w;
            }
            {
                const float4 wl = *(const float4*)&s_w2[(kk + 2) * 128 + jlo];
                const float4 wh = *(const float4*)&s_w2[(kk + 2) * 128 + jhi];
                acc0 += hq.z * wl.x; acc1 += hq.z * wl.y; acc2 += hq.z * wl.z; acc3 += hq.z * wl.w;
                acc4 += hq.z * wh.x; acc5 += hq.z * wh.y; acc6 += hq.z * wh.z; acc7 += hq.z * wh.w;
            }
            {
                const float4 wl = *(const float4*)&s_w2[(kk + 3) * 128 + jlo];
                const float4 wh = *(const float4*)&s_w2[(kk + 3) * 128 + jhi];
                acc0 += hq.w * wl.x; acc1 += hq.w * wl.y; acc2 += hq.w * wl.z; acc3 += hq.w * wl.w;
                acc4 += hq.w * wh.x; acc5 += hq.w * wh.y; acc6 += hq.w * wh.z; acc7 += hq.w * wh.w;
            }
        }

        const float h20 = leaky(acc0 + b2_lo.x);
        const float h21 = leaky(acc1 + b2_lo.y);
        const float h22 = leaky(acc2 + b2_lo.z);
        const float h23 = leaky(acc3 + b2_lo.w);
        const float h24 = leaky(acc4 + b2_hi.x);
        const float h25 = leaky(acc5 + b2_hi.y);
        const float h26 = leaky(acc6 + b2_hi.z);
        const float h27 = leaky(acc7 + b2_hi.w);

        float fp = h20 * wf_lo.x + h21 * wf_lo.y + h22 * wf_lo.z + h23 * wf_lo.w
                 + h24 * wf_hi.x + h25 * wf_hi.y + h26 * wf_hi.z + h27 * wf_hi.w;
        float mq = h20 * wm_lo.x + h21 * wm_lo.y + h22 * wm_lo.z + h23 * wm_lo.w
                 + h24 * wm_hi.x + h25 * wm_hi.y + h26 * wm_hi.z + h27 * wm_hi.w;
        fp += __shfl_xor(fp, 1); fp += __shfl_xor(fp, 2);
        fp += __shfl_xor(fp, 4); fp += __shfl_xor(fp, 8);
        mq += __shfl_xor(mq, 1); mq += __shfl_xor(mq, 2);
        mq += __shfl_xor(mq, 4); mq += __shfl_xor(mq, 8);

        const float f_sc = fminf(fmaxf(fp + bfv, -20.0f), 20.0f);
        const float m_sc = fminf(fmaxf(mq + bmv, -20.0f), 20.0f);
        const float dsc = 5.0f * (f_sc - m_sc);
        float fatt;
        if (dsc >= 0.0f) { const float e = __expf(-dsc); fatt = 1.0f / (1.0f + e); }
        else             { const float e = __expf(dsc);  fatt = e / (1.0f + e); }
        const float matt = 1.0f - fatt;

        const float efa = idm_act_f(ego_v, ef_dv, ef_dx, inv_v0, p_tg, p_jam, p_amax, inv_gd);
        const float ema = idm_act_f(ego_v, em_dv, em_dx, inv_v0, p_tg, p_jam, p_amax, inv_gd);
        const float a2n = fatt * efa + matt * ema;

        const float delta = ego_v * 0.1f + 0.005f * a2n;
        disp  += delta;
        ego_x += delta;
        ego_v += a2n * 0.1f;
        ego_a  = a2n;

        if (sidx == 0) {
            out_disp[b * 51 + t + 1] = disp;
            out_act [b * 50 + t]     = a2n;
            out_fat [b * 50 + t]     = fatt;
            out_mat [b * 50 + t]     = matt;
        }
    }
}

extern "C" void kernel_launch(void* const* d_in, const int* in_sizes, int n_in,
                              void* d_out, int out_size, void* d_ws, size_t ws_size,
                              hipStream_t stream) {
    (void)in_sizes; (void)n_in; (void)d_ws; (void)ws_size; (void)out_size;
    const float* idm_params  = (const float*)d_in[0];
    const float* proj_latent = (const float*)d_in[1];
    const float* enc_h       = (const float*)d_in[2];
    const float* idm_s       = (const float*)d_in[3];
    const float* merger_cs   = (const float*)d_in[4];
    const float* scaler_mean = (const float*)d_in[5];
    const float* scaler_var  = (const float*)d_in[6];
    const float* W1          = (const float*)d_in[7];
    const float* b1          = (const float*)d_in[8];
    const float* W2          = (const float*)d_in[9];
    const float* b2          = (const float*)d_in[10];
    const float* Wf          = (const float*)d_in[11];
    const float* bfp         = (const float*)d_in[12];
    const float* Wm          = (const float*)d_in[13];
    const float* bmp         = (const float*)d_in[14];

    idm_rollout_kernel<<<dim3(NB / 16), dim3(256), 0, stream>>>(
        idm_params, proj_latent, enc_h, idm_s, merger_cs,
        scaler_mean, scaler_var, W1, b1, W2, b2, Wf, bfp, Wm, bmp,
        (float*)d_out);
}